// Round 2
// baseline (407.630 us; speedup 1.0000x reference)
//
#include <hip/hip_runtime.h>
#include <math.h>

#define B_ 2
#define N_ 2048
#define D_ 1024
#define H_ 16
#define M_ (B_*N_)

typedef unsigned short u16;
typedef short bf16x8 __attribute__((ext_vector_type(8)));
typedef float f32x4 __attribute__((ext_vector_type(4)));

struct Ptr5 { const float* p[5]; };
struct GammaArg { float lg2[16]; };

static __device__ inline u16 f2bf(float f) {
  union { float f; unsigned u; } x; x.f = f;
  unsigned u = x.u;
  unsigned r = (u + 0x7fffu + ((u >> 16) & 1u)) >> 16;
  return (u16)r;
}
static __device__ inline bf16x8 ld8(const u16* p) {
  uint4 u = *(const uint4*)(p);
  return *reinterpret_cast<bf16x8*>(&u);
}

// ---------- batch stats of x (sum, sumsq) ----------
__global__ void k_batch_stats_partial(const float* __restrict__ x, double* __restrict__ part) {
  int b = blockIdx.y, c = blockIdx.x, t = threadIdx.x;
  const float* p = x + (size_t)b*(N_*D_) + (size_t)c*32768;
  double s = 0.0, s2 = 0.0;
  for (int it = 0; it < 32; ++it) {
    float4 v = *(const float4*)(p + it*1024 + t*4);
    s  += (double)v.x + (double)v.y + (double)v.z + (double)v.w;
    s2 += (double)v.x*v.x + (double)v.y*v.y + (double)v.z*v.z + (double)v.w*v.w;
  }
  for (int o = 32; o > 0; o >>= 1) { s += __shfl_down(s,o); s2 += __shfl_down(s2,o); }
  __shared__ double lds[8];
  int w = t>>6, l = t&63;
  if (l==0) { lds[w*2]=s; lds[w*2+1]=s2; }
  __syncthreads();
  if (t==0) {
    part[(b*64+c)*2]   = lds[0]+lds[2]+lds[4]+lds[6];
    part[(b*64+c)*2+1] = lds[1]+lds[3]+lds[5]+lds[7];
  }
}

__global__ void k_batch_stats_final(const double* __restrict__ part, float* __restrict__ stats) {
  int b = blockIdx.x, t = threadIdx.x; // 64 threads
  double s = part[(b*64+t)*2], s2 = part[(b*64+t)*2+1];
  for (int o = 32; o > 0; o >>= 1) { s += __shfl_down(s,o); s2 += __shfl_down(s2,o); }
  if (t==0) {
    double inv = 1.0/(double)(N_*D_);
    double mu = s*inv, var = s2*inv - mu*mu;
    stats[b*2]   = (float)mu;
    stats[b*2+1] = rsqrtf((float)var + 1e-5f);
  }
}

// ---------- weight abs-mean ----------
__global__ void k_wmean_partial(Ptr5 W, double* __restrict__ part) {
  int wi = blockIdx.y, c = blockIdx.x, t = threadIdx.x;
  const float* p = W.p[wi] + (size_t)c*65536;
  double s = 0.0;
  for (int it = 0; it < 64; ++it) {
    float4 v = *(const float4*)(p + it*1024 + t*4);
    s += fabs((double)v.x)+fabs((double)v.y)+fabs((double)v.z)+fabs((double)v.w);
  }
  for (int o = 32; o > 0; o >>= 1) s += __shfl_down(s,o);
  __shared__ double lds[4];
  if ((t&63)==0) lds[t>>6]=s;
  __syncthreads();
  if (t==0) part[wi*16+c] = lds[0]+lds[1]+lds[2]+lds[3];
}

__global__ void k_wmean_final(const double* __restrict__ part, float* __restrict__ mw, float* __restrict__ invmw) {
  int wi = blockIdx.x, t = threadIdx.x;
  double s = (t<16) ? part[wi*16+t] : 0.0;
  for (int o = 8; o > 0; o >>= 1) s += __shfl_down(s,o);
  if (t==0) {
    double mean = s / (double)(D_*D_);
    float mwc = fmaxf((float)mean, 1e-5f);
    mw[wi] = mwc;
    invmw[wi] = 1.0f/mwc;
  }
}

__global__ void k_ternarize(Ptr5 W, const float* __restrict__ invmw, u16* __restrict__ wt) {
  int wi = blockIdx.y;
  float inv = invmw[wi];
  size_t off = (size_t)blockIdx.x*1024 + threadIdx.x*4;
  float4 v = *(const float4*)(W.p[wi] + off);
  ushort4 o4;
  o4.x = f2bf(fminf(fmaxf(rintf(v.x*inv),-1.f),1.f));
  o4.y = f2bf(fminf(fmaxf(rintf(v.y*inv),-1.f),1.f));
  o4.z = f2bf(fminf(fmaxf(rintf(v.z*inv),-1.f),1.f));
  o4.w = f2bf(fminf(fmaxf(rintf(v.w*inv),-1.f),1.f));
  *(ushort4*)(wt + (size_t)wi*(D_*D_) + off) = o4;
}

// ---------- per-row activation quant (shared LN stats) ----------
__global__ void k_quant_rows(const float* __restrict__ in, const float* __restrict__ stats,
                             u16* __restrict__ q, float* __restrict__ rowscale) {
  int m = blockIdx.x, t = threadIdx.x;
  int b = m >> 11;
  float mu = stats[b*2], rstd = stats[b*2+1];
  float4 v = *(const float4*)(in + (size_t)m*D_ + t*4);
  float xn0 = (v.x-mu)*rstd, xn1 = (v.y-mu)*rstd, xn2 = (v.z-mu)*rstd, xn3 = (v.w-mu)*rstd;
  float am = fmaxf(fmaxf(fabsf(xn0),fabsf(xn1)),fmaxf(fabsf(xn2),fabsf(xn3)));
  for (int o = 32; o > 0; o >>= 1) am = fmaxf(am, __shfl_xor(am,o));
  __shared__ float wm[4];
  int w = t>>6, l = t&63;
  if (l==0) wm[w]=am;
  __syncthreads();
  am = fmaxf(fmaxf(wm[0],wm[1]),fmaxf(wm[2],wm[3]));
  float clipped = fmaxf(am, 1e-5f);
  float sc = 127.0f/clipped;
  ushort4 o4;
  o4.x = f2bf(fminf(fmaxf(rintf(xn0*sc),-128.f),127.f));
  o4.y = f2bf(fminf(fmaxf(rintf(xn1*sc),-128.f),127.f));
  o4.z = f2bf(fminf(fmaxf(rintf(xn2*sc),-128.f),127.f));
  o4.w = f2bf(fminf(fmaxf(rintf(xn3*sc),-128.f),127.f));
  *(ushort4*)(q + (size_t)m*D_ + t*4) = o4;
  if (t==0) rowscale[m] = clipped/127.0f;
}

// ---------- MFMA GEMM: out[m,d] = (A[m,:] . Bt[d,:]) * rowscale[m] * mw[widx] ----------
// mode 0: store f32 [M,D]; mode 1: silu then f32; mode 2: bf16 scattered to [B,H,N,64]
__global__ __launch_bounds__(256) void k_gemm(const u16* __restrict__ A, const u16* __restrict__ Bt,
                       const float* __restrict__ rowscale, const float* __restrict__ mw, int widx,
                       float* __restrict__ outF, u16* __restrict__ outH, int mode) {
  __shared__ u16 As[128][40];
  __shared__ u16 Bs[64][40];
  int tid = threadIdx.x;
  int m0 = blockIdx.x*128, n0 = blockIdx.y*64;
  int w = tid>>6, l = tid&63;
  int wm = (w>>1)*64, wn = (w&1)*32;
  int lr = l&15, lk = (l>>4)*8;
  f32x4 acc[4][2];
  for (int i=0;i<4;++i) for (int j=0;j<2;++j) acc[i][j] = (f32x4){0.f,0.f,0.f,0.f};
  for (int k0 = 0; k0 < D_; k0 += 32) {
    {
      int row = tid>>2, seg = tid&3;
      *(uint4*)&As[row][seg*8] = *(const uint4*)(A + (size_t)(m0+row)*D_ + k0 + seg*8);
      int id2 = tid+256; int row2 = id2>>2, seg2 = id2&3;
      *(uint4*)&As[row2][seg2*8] = *(const uint4*)(A + (size_t)(m0+row2)*D_ + k0 + seg2*8);
      *(uint4*)&Bs[row][seg*8] = *(const uint4*)(Bt + (size_t)(n0+row)*D_ + k0 + seg*8);
    }
    __syncthreads();
    bf16x8 a[4], b[2];
    for (int i=0;i<4;++i) a[i] = *(bf16x8*)&As[wm + i*16 + lr][lk];
    for (int j=0;j<2;++j) b[j] = *(bf16x8*)&Bs[wn + j*16 + lr][lk];
    for (int i=0;i<4;++i)
      for (int j=0;j<2;++j)
        acc[i][j] = __builtin_amdgcn_mfma_f32_16x16x32_bf16(a[i], b[j], acc[i][j], 0, 0, 0);
    __syncthreads();
  }
  float sw = mw[widx];
  for (int i=0;i<4;++i) {
    for (int j=0;j<2;++j) {
      #pragma unroll
      for (int r=0;r<4;++r) {
        int row = m0 + wm + i*16 + ((l>>4)<<2) + r;
        int col = n0 + wn + j*16 + lr;
        float v = acc[i][j][r] * rowscale[row] * sw;
        if (mode == 0) {
          outF[(size_t)row*D_ + col] = v;
        } else if (mode == 1) {
          outF[(size_t)row*D_ + col] = v / (1.0f + expf(-v));
        } else {
          int bb = row >> 11, n = row & 2047, h = col >> 6, e = col & 63;
          outH[(((size_t)(bb*H_ + h))*N_ + n)*64 + e] = f2bf(v);
        }
      }
    }
  }
}

// ---------- retention: y[b,h,n,:] = sum_{m<=n} (q.k)*0.125*gamma^(n-m) * v[m,:] ----------
__global__ __launch_bounds__(256) void k_attn(const u16* __restrict__ qh, const u16* __restrict__ kh,
                       const u16* __restrict__ vh, float* __restrict__ y, GammaArg G) {
  __shared__ u16 vt[64][72];
  __shared__ u16 pl[4][16][72];
  int qt = blockIdx.x, bh = blockIdx.y;
  int b = bh >> 4, h = bh & 15;
  float lg = G.lg2[h];
  int tid = threadIdx.x, w = tid>>6, l = tid&63;
  int lr = l&15, lkg = l>>4;
  const size_t base = (size_t)bh * (N_*64);
  bf16x8 qa[2];
  {
    int n = qt*64 + w*16 + lr;
    const u16* qp = qh + base + (size_t)n*64 + lkg*8;
    qa[0] = ld8(qp);
    qa[1] = ld8(qp + 32);
  }
  f32x4 yacc[4];
  for (int eb=0; eb<4; ++eb) yacc[eb] = (f32x4){0.f,0.f,0.f,0.f};
  int nrow = qt*64 + w*16 + lkg*4;
  for (int t = 0; t <= qt; ++t) {
    __syncthreads();
    // stage V^T into LDS
    for (int rr = 0; rr < 2; ++rr) {
      int m = (tid>>3) + rr*32;
      int e0 = (tid&7)*8;
      uint4 vv = *(const uint4*)(vh + base + (size_t)(t*64+m)*64 + e0);
      u16* vs = (u16*)&vv;
      #pragma unroll
      for (int j = 0; j < 8; ++j) vt[e0+j][m] = vs[j];
    }
    __syncthreads();
    // S = Q K^T  (16x64 per wave)
    f32x4 sacc[4];
    for (int c=0;c<4;++c) sacc[c] = (f32x4){0.f,0.f,0.f,0.f};
    for (int c=0;c<4;++c) {
      int mg = t*64 + c*16 + lr;
      const u16* kp = kh + base + (size_t)mg*64 + lkg*8;
      sacc[c] = __builtin_amdgcn_mfma_f32_16x16x32_bf16(qa[0], ld8(kp),    sacc[c], 0,0,0);
      sacc[c] = __builtin_amdgcn_mfma_f32_16x16x32_bf16(qa[1], ld8(kp+32), sacc[c], 0,0,0);
    }
    // decay + causal mask, write P strip (wave-private)
    for (int c=0;c<4;++c) {
      int mg = t*64 + c*16 + lr;
      #pragma unroll
      for (int r=0;r<4;++r) {
        int d = nrow + r - mg;
        float p = (d >= 0) ? sacc[c][r]*0.125f*exp2f((float)d*lg) : 0.0f;
        pl[w][lkg*4+r][c*16+lr] = f2bf(p);
      }
    }
    // PV
    for (int kk=0;kk<2;++kk) {
      bf16x8 pa = *(bf16x8*)&pl[w][lr][kk*32 + lkg*8];
      #pragma unroll
      for (int eb=0;eb<4;++eb) {
        bf16x8 vb = *(bf16x8*)&vt[eb*16+lr][kk*32 + lkg*8];
        yacc[eb] = __builtin_amdgcn_mfma_f32_16x16x32_bf16(pa, vb, yacc[eb], 0,0,0);
      }
    }
  }
  for (int eb=0;eb<4;++eb) {
    #pragma unroll
    for (int r=0;r<4;++r) {
      int n = nrow + r;
      int col = h*64 + eb*16 + lr;
      y[((size_t)(b*N_+n))*D_ + col] = yacc[eb][r];
    }
  }
}

// ---------- row LayerNorm(y)*g -> z, plus per-row z sums ----------
__global__ void k_ln_mul(const float* __restrict__ y, const float* __restrict__ g,
                         const float* __restrict__ lnw, const float* __restrict__ lnb,
                         float* __restrict__ z, double* __restrict__ zrow) {
  int m = blockIdx.x, t = threadIdx.x;
  float4 v = *(const float4*)(y + (size_t)m*D_ + t*4);
  double s  = (double)v.x + (double)v.y + (double)v.z + (double)v.w;
  double s2 = (double)v.x*v.x + (double)v.y*v.y + (double)v.z*v.z + (double)v.w*v.w;
  __shared__ double lds[8];
  int w = t>>6, l = t&63;
  for (int o = 32; o > 0; o >>= 1) { s += __shfl_down(s,o); s2 += __shfl_down(s2,o); }
  if (l==0) { lds[w*2]=s; lds[w*2+1]=s2; }
  __syncthreads();
  double ts = lds[0]+lds[2]+lds[4]+lds[6], ts2 = lds[1]+lds[3]+lds[5]+lds[7];
  float mu = (float)(ts/(double)D_);
  float var = (float)(ts2/(double)D_) - mu*mu;
  float rstd = rsqrtf(var + 1e-5f);
  float4 gv = *(const float4*)(g + (size_t)m*D_ + t*4);
  float4 lw = *(const float4*)(lnw + t*4);
  float4 lb = *(const float4*)(lnb + t*4);
  float z0 = ((v.x-mu)*rstd*lw.x + lb.x)*gv.x;
  float z1 = ((v.y-mu)*rstd*lw.y + lb.y)*gv.y;
  float z2 = ((v.z-mu)*rstd*lw.z + lb.z)*gv.z;
  float z3 = ((v.w-mu)*rstd*lw.w + lb.w)*gv.w;
  float4 zo; zo.x=z0; zo.y=z1; zo.z=z2; zo.w=z3;
  *(float4*)(z + (size_t)m*D_ + t*4) = zo;
  double zs  = (double)z0 + (double)z1 + (double)z2 + (double)z3;
  double zs2 = (double)z0*z0 + (double)z1*z1 + (double)z2*z2 + (double)z3*z3;
  for (int o = 32; o > 0; o >>= 1) { zs += __shfl_down(zs,o); zs2 += __shfl_down(zs2,o); }
  __syncthreads();
  if (l==0) { lds[w*2]=zs; lds[w*2+1]=zs2; }
  __syncthreads();
  if (t==0) {
    zrow[m*2]   = lds[0]+lds[2]+lds[4]+lds[6];
    zrow[m*2+1] = lds[1]+lds[3]+lds[5]+lds[7];
  }
}

__global__ void k_zstats_final(const double* __restrict__ zrow, float* __restrict__ stats) {
  int b = blockIdx.x, t = threadIdx.x; // 256
  double s=0.0, s2=0.0;
  for (int k=0;k<8;++k) {
    int m = b*2048 + k*256 + t;
    s += zrow[m*2]; s2 += zrow[m*2+1];
  }
  for (int o = 32; o > 0; o >>= 1) { s += __shfl_down(s,o); s2 += __shfl_down(s2,o); }
  __shared__ double lds[8];
  int w = t>>6, l = t&63;
  if (l==0) { lds[w*2]=s; lds[w*2+1]=s2; }
  __syncthreads();
  if (t==0) {
    double ts = lds[0]+lds[2]+lds[4]+lds[6], ts2 = lds[1]+lds[3]+lds[5]+lds[7];
    double inv = 1.0/(double)(N_*D_);
    double mu = ts*inv, var = ts2*inv - mu*mu;
    stats[b*2]   = (float)mu;
    stats[b*2+1] = rsqrtf((float)var + 1e-5f);
  }
}

extern "C" void kernel_launch(void* const* d_in, const int* in_sizes, int n_in,
                              void* d_out, int out_size, void* d_ws, size_t ws_size,
                              hipStream_t stream) {
  const float* x = (const float*)d_in[0];
  Ptr5 W;
  for (int i = 0; i < 5; ++i) W.p[i] = (const float*)d_in[1+i];
  const float* lnw = (const float*)d_in[6];
  const float* lnb = (const float*)d_in[7];

  char* ws = (char*)d_ws;
  float*  xstats = (float*)(ws + 0);
  float*  zstats = (float*)(ws + 64);
  float*  mw     = (float*)(ws + 128);
  float*  invmw  = (float*)(ws + 192);
  double* part1  = (double*)(ws + 256);      // 128*2 doubles
  double* wpart  = (double*)(ws + 2304);     // 80 doubles
  float*  inv1   = (float*)(ws + 3072);      // 4096
  float*  inv2   = (float*)(ws + 19456);     // 4096
  double* zrow   = (double*)(ws + 35840);    // 4096*2
  u16*    wt     = (u16*)(ws + 101376);      // 5*1M bf16
  u16*    qx     = (u16*)(ws + 10587136);    // 4096x1024 bf16
  u16*    qh     = (u16*)(ws + 18975744);
  u16*    kh     = (u16*)(ws + 27364352);
  u16*    vh     = (u16*)(ws + 35752960);
  float*  gbuf   = (float*)(ws + 44141568);
  float*  ybuf   = (float*)(ws + 60918784);
  float*  zbuf   = (float*)(ws + 77696000);
  u16*    qz     = qx; // reuse

  GammaArg G;
  {
    double l0 = log(1.0/32.0), l1 = log(1.0/512.0);
    for (int h = 0; h < 16; ++h) {
      float t = (float)(l0 + (l1-l0)*((double)h/15.0));
      float gm = 1.0f - expf(t);
      G.lg2[h] = (float)log2((double)gm);
    }
  }

  dim3 b256(256);
  hipLaunchKernelGGL(k_batch_stats_partial, dim3(64, B_), b256, 0, stream, x, part1);
  hipLaunchKernelGGL(k_batch_stats_final, dim3(B_), dim3(64), 0, stream, part1, xstats);
  hipLaunchKernelGGL(k_wmean_partial, dim3(16, 5), b256, 0, stream, W, wpart);
  hipLaunchKernelGGL(k_wmean_final, dim3(5), dim3(64), 0, stream, wpart, mw, invmw);
  hipLaunchKernelGGL(k_ternarize, dim3(1024, 5), b256, 0, stream, W, invmw, wt);
  hipLaunchKernelGGL(k_quant_rows, dim3(M_), b256, 0, stream, x, xstats, qx, inv1);

  hipLaunchKernelGGL(k_gemm, dim3(32,16), b256, 0, stream, qx, wt + (size_t)0*1048576, inv1, mw, 0, (float*)nullptr, qh, 2);
  hipLaunchKernelGGL(k_gemm, dim3(32,16), b256, 0, stream, qx, wt + (size_t)1*1048576, inv1, mw, 1, (float*)nullptr, kh, 2);
  hipLaunchKernelGGL(k_gemm, dim3(32,16), b256, 0, stream, qx, wt + (size_t)2*1048576, inv1, mw, 2, (float*)nullptr, vh, 2);
  hipLaunchKernelGGL(k_gemm, dim3(32,16), b256, 0, stream, qx, wt + (size_t)3*1048576, inv1, mw, 3, gbuf, (u16*)nullptr, 1);

  hipLaunchKernelGGL(k_attn, dim3(32, 32), b256, 0, stream, qh, kh, vh, ybuf, G);

  hipLaunchKernelGGL(k_ln_mul, dim3(M_), b256, 0, stream, ybuf, gbuf, lnw, lnb, zbuf, zrow);
  hipLaunchKernelGGL(k_zstats_final, dim3(B_), b256, 0, stream, zrow, zstats);
  hipLaunchKernelGGL(k_quant_rows, dim3(M_), b256, 0, stream, zbuf, zstats, qz, inv2);
  hipLaunchKernelGGL(k_gemm, dim3(32,16), b256, 0, stream, qz, wt + (size_t)4*1048576, inv2, mw, 4, (float*)d_out, (u16*)nullptr, 0);
}

// Round 4
// 330.242 us; speedup vs baseline: 1.2343x; 1.2343x over previous
//
#include <hip/hip_runtime.h>
#include <math.h>

#define B_ 2
#define N_ 2048
#define D_ 1024
#define H_ 16
#define M_ (B_*N_)

typedef unsigned short u16;
typedef unsigned int u32;
typedef short bf16x8 __attribute__((ext_vector_type(8)));
typedef float f32x4 __attribute__((ext_vector_type(4)));

struct Ptr5 { const float* p[5]; };
struct GammaArg { float lg2[16]; };

static __device__ inline u16 f2bf(float f) {
  union { float f; unsigned u; } x; x.f = f;
  unsigned u = x.u;
  unsigned r = (u + 0x7fffu + ((u >> 16) & 1u)) >> 16;
  return (u16)r;
}
static __device__ inline bf16x8 ld8(const u16* p) {
  uint4 u = *(const uint4*)(p);
  return *reinterpret_cast<bf16x8*>(&u);
}
#define GLDS(g, l) __builtin_amdgcn_global_load_lds((const __attribute__((address_space(1))) u32*)(g), (__attribute__((address_space(3))) u32*)(l), 16, 0, 0)

// ---------- batch stats of x (sum, sumsq) ----------
__global__ void k_batch_stats_partial(const float* __restrict__ x, double* __restrict__ part) {
  int b = blockIdx.y, c = blockIdx.x, t = threadIdx.x;
  const float* p = x + (size_t)b*(N_*D_) + (size_t)c*32768;
  double s = 0.0, s2 = 0.0;
  for (int it = 0; it < 32; ++it) {
    float4 v = *(const float4*)(p + it*1024 + t*4);
    s  += (double)v.x + (double)v.y + (double)v.z + (double)v.w;
    s2 += (double)v.x*v.x + (double)v.y*v.y + (double)v.z*v.z + (double)v.w*v.w;
  }
  for (int o = 32; o > 0; o >>= 1) { s += __shfl_down(s,o); s2 += __shfl_down(s2,o); }
  __shared__ double lds[8];
  int w = t>>6, l = t&63;
  if (l==0) { lds[w*2]=s; lds[w*2+1]=s2; }
  __syncthreads();
  if (t==0) {
    part[(b*64+c)*2]   = lds[0]+lds[2]+lds[4]+lds[6];
    part[(b*64+c)*2+1] = lds[1]+lds[3]+lds[5]+lds[7];
  }
}

__global__ void k_batch_stats_final(const double* __restrict__ part, float* __restrict__ stats) {
  int b = blockIdx.x, t = threadIdx.x; // 64 threads
  double s = part[(b*64+t)*2], s2 = part[(b*64+t)*2+1];
  for (int o = 32; o > 0; o >>= 1) { s += __shfl_down(s,o); s2 += __shfl_down(s2,o); }
  if (t==0) {
    double inv = 1.0/(double)(N_*D_);
    double mu = s*inv, var = s2*inv - mu*mu;
    stats[b*2]   = (float)mu;
    stats[b*2+1] = rsqrtf((float)var + 1e-5f);
  }
}

// ---------- weight abs-mean ----------
__global__ void k_wmean_partial(Ptr5 W, double* __restrict__ part) {
  int wi = blockIdx.y, c = blockIdx.x, t = threadIdx.x;
  const float* p = W.p[wi] + (size_t)c*65536;
  double s = 0.0;
  for (int it = 0; it < 64; ++it) {
    float4 v = *(const float4*)(p + it*1024 + t*4);
    s += fabs((double)v.x)+fabs((double)v.y)+fabs((double)v.z)+fabs((double)v.w);
  }
  for (int o = 32; o > 0; o >>= 1) s += __shfl_down(s,o);
  __shared__ double lds[4];
  if ((t&63)==0) lds[t>>6]=s;
  __syncthreads();
  if (t==0) part[wi*16+c] = lds[0]+lds[1]+lds[2]+lds[3];
}

__global__ void k_wmean_final(const double* __restrict__ part, float* __restrict__ mw, float* __restrict__ invmw) {
  int wi = blockIdx.x, t = threadIdx.x;
  double s = (t<16) ? part[wi*16+t] : 0.0;
  for (int o = 8; o > 0; o >>= 1) s += __shfl_down(s,o);
  if (t==0) {
    double mean = s / (double)(D_*D_);
    float mwc = fmaxf((float)mean, 1e-5f);
    mw[wi] = mwc;
    invmw[wi] = 1.0f/mwc;
  }
}

__global__ void k_ternarize(Ptr5 W, const float* __restrict__ invmw, u16* __restrict__ wt) {
  int wi = blockIdx.y;
  float inv = invmw[wi];
  size_t off = (size_t)blockIdx.x*1024 + threadIdx.x*4;
  float4 v = *(const float4*)(W.p[wi] + off);
  ushort4 o4;
  o4.x = f2bf(fminf(fmaxf(rintf(v.x*inv),-1.f),1.f));
  o4.y = f2bf(fminf(fmaxf(rintf(v.y*inv),-1.f),1.f));
  o4.z = f2bf(fminf(fmaxf(rintf(v.z*inv),-1.f),1.f));
  o4.w = f2bf(fminf(fmaxf(rintf(v.w*inv),-1.f),1.f));
  *(ushort4*)(wt + (size_t)wi*(D_*D_) + off) = o4;
}

// ---------- per-row activation quant (shared LN stats) ----------
__global__ void k_quant_rows(const float* __restrict__ in, const float* __restrict__ stats,
                             u16* __restrict__ q, float* __restrict__ rowscale) {
  int m = blockIdx.x, t = threadIdx.x;
  int b = m >> 11;
  float mu = stats[b*2], rstd = stats[b*2+1];
  float4 v = *(const float4*)(in + (size_t)m*D_ + t*4);
  float xn0 = (v.x-mu)*rstd, xn1 = (v.y-mu)*rstd, xn2 = (v.z-mu)*rstd, xn3 = (v.w-mu)*rstd;
  float am = fmaxf(fmaxf(fabsf(xn0),fabsf(xn1)),fmaxf(fabsf(xn2),fabsf(xn3)));
  for (int o = 32; o > 0; o >>= 1) am = fmaxf(am, __shfl_xor(am,o));
  __shared__ float wm[4];
  int w = t>>6, l = t&63;
  if (l==0) wm[w]=am;
  __syncthreads();
  am = fmaxf(fmaxf(wm[0],wm[1]),fmaxf(wm[2],wm[3]));
  float clipped = fmaxf(am, 1e-5f);
  float sc = 127.0f/clipped;
  ushort4 o4;
  o4.x = f2bf(fminf(fmaxf(rintf(xn0*sc),-128.f),127.f));
  o4.y = f2bf(fminf(fmaxf(rintf(xn1*sc),-128.f),127.f));
  o4.z = f2bf(fminf(fmaxf(rintf(xn2*sc),-128.f),127.f));
  o4.w = f2bf(fminf(fmaxf(rintf(xn3*sc),-128.f),127.f));
  *(ushort4*)(q + (size_t)m*D_ + t*4) = o4;
  if (t==0) rowscale[m] = clipped/127.0f;
}

// ---------- MFMA GEMM (128x64 tile, BK=32, global_load_lds staging) ----------
// mode 0: f32 [M,D]; mode 1: silu f32; mode 2: bf16 [B,H,N,64]; mode 3: bf16 transposed [B,H,64,N]
__global__ __launch_bounds__(256) void k_gemm(const u16* __restrict__ A, const u16* __restrict__ Bt,
                       const float* __restrict__ rowscale, const float* __restrict__ mw, int widx,
                       float* __restrict__ outF, u16* __restrict__ outH, int mode) {
  __shared__ u16 As[128*32];
  __shared__ u16 Bs[64*32];
  int tid = threadIdx.x;
  int m0 = blockIdx.x*128, n0 = blockIdx.y*64;
  int w = tid>>6, l = tid&63;
  int wm = (w>>1)*64, wn = (w&1)*32;
  int lr = l&15, lkg = l>>4;
  f32x4 acc[4][2];
  for (int i=0;i<4;++i) for (int j=0;j<2;++j) acc[i][j] = (f32x4){0.f,0.f,0.f,0.f};
  // chunk mapping for staging: chunk c -> row=c>>2, seg=c&3 (16B segs)
  int c0 = tid, c1 = tid + 256;
  const u16* ga0 = A  + (size_t)(m0 + (c0>>2))*D_ + (c0&3)*8;
  const u16* ga1 = A  + (size_t)(m0 + (c1>>2))*D_ + (c1&3)*8;
  const u16* gb0 = Bt + (size_t)(n0 + (c0>>2))*D_ + (c0&3)*8;
  for (int k0 = 0; k0 < D_; k0 += 32) {
    __syncthreads();
    GLDS(ga0 + k0, &As[w*512]);
    GLDS(ga1 + k0, &As[2048 + w*512]);
    GLDS(gb0 + k0, &Bs[w*512]);
    __syncthreads();
    bf16x8 a[4], b[2];
    for (int i=0;i<4;++i) a[i] = ld8(&As[(wm + i*16 + lr)*32 + lkg*8]);
    for (int j=0;j<2;++j) b[j] = ld8(&Bs[(wn + j*16 + lr)*32 + lkg*8]);
    for (int i=0;i<4;++i)
      for (int j=0;j<2;++j)
        acc[i][j] = __builtin_amdgcn_mfma_f32_16x16x32_bf16(a[i], b[j], acc[i][j], 0, 0, 0);
  }
  float sw = mw[widx];
  for (int i=0;i<4;++i) {
    int rowb = m0 + wm + i*16 + lkg*4;
    for (int j=0;j<2;++j) {
      int col = n0 + wn + j*16 + lr;
      float vv[4];
      #pragma unroll
      for (int r=0;r<4;++r) vv[r] = acc[i][j][r] * rowscale[rowb+r] * sw;
      if (mode == 0) {
        #pragma unroll
        for (int r=0;r<4;++r) outF[(size_t)(rowb+r)*D_ + col] = vv[r];
      } else if (mode == 1) {
        #pragma unroll
        for (int r=0;r<4;++r) outF[(size_t)(rowb+r)*D_ + col] = vv[r] / (1.0f + expf(-vv[r]));
      } else if (mode == 2) {
        int bb = rowb >> 11, h = col >> 6, e = col & 63;
        #pragma unroll
        for (int r=0;r<4;++r) {
          int n = (rowb+r) & 2047;
          outH[(((size_t)(bb*H_ + h))*N_ + n)*64 + e] = f2bf(vv[r]);
        }
      } else {
        // transposed V: [B,H,64,N]
        int bb = rowb >> 11, h = col >> 6, e = col & 63;
        int n4 = rowb & 2047;
        ushort4 pk;
        pk.x = f2bf(vv[0]); pk.y = f2bf(vv[1]); pk.z = f2bf(vv[2]); pk.w = f2bf(vv[3]);
        *(ushort4*)&outH[(((size_t)(bb*H_ + h))*64 + e)*N_ + n4] = pk;
      }
    }
  }
}

// ---------- retention: y[b,h,n,:] = sum_{m<=n} (q.k)*0.125*gamma^(n-m) * v[m,:] ----------
// vhT layout: [B,H,64,N] (transposed V). Block bx handles qt = bx and qt = 31-bx.
__global__ __launch_bounds__(256) void k_attn(const u16* __restrict__ qh, const u16* __restrict__ kh,
                       const u16* __restrict__ vhT, float* __restrict__ y, GammaArg G) {
  __shared__ u16 vt[64][72];
  __shared__ u16 pl[4][16][76];
  int bx = blockIdx.x, bh = blockIdx.y;
  int b = bh >> 4, h = bh & 15;
  float lg = G.lg2[h];
  int tid = threadIdx.x, w = tid>>6, l = tid&63;
  int lr = l&15, lkg = l>>4;
  const size_t base = (size_t)bh * (N_*64);
  int nl_base = w*16 + lkg*4;
  // separable decay factors: fac[c][r] = 0.125 * gamma^(nl - ml)
  float fac[4][4];
  #pragma unroll
  for (int c=0;c<4;++c)
    #pragma unroll
    for (int r=0;r<4;++r)
      fac[c][r] = 0.125f * exp2f((float)((nl_base + r) - (c*16 + lr)) * lg);
  float g64inv = exp2f(-64.0f * lg);
  for (int pass = 0; pass < 2; ++pass) {
    int qt = pass ? (31 - bx) : bx;
    bf16x8 qa[2];
    {
      int n = qt*64 + w*16 + lr;
      const u16* qp = qh + base + (size_t)n*64 + lkg*8;
      qa[0] = ld8(qp);
      qa[1] = ld8(qp + 32);
    }
    f32x4 yacc[4];
    for (int eb=0; eb<4; ++eb) yacc[eb] = (f32x4){0.f,0.f,0.f,0.f};
    float tf = exp2f(64.0f * (float)qt * lg);   // gamma^(64*(qt-t)) at t=0
    int nrow = qt*64 + nl_base;
    for (int t = 0; t <= qt; ++t) {
      __syncthreads();
      // stage V^T tile (rows e, cols t*64..t*64+63) — coalesced, linear ds_write_b128
      {
        const u16* vsrc = vhT + base + (size_t)t*64;
        int ca = tid, cb = tid + 256;  // chunk: row=c>>3, seg=c&7
        uint4 u0 = *(const uint4*)(vsrc + (size_t)(ca>>3)*N_ + (ca&7)*8);
        uint4 u1 = *(const uint4*)(vsrc + (size_t)(cb>>3)*N_ + (cb&7)*8);
        *(uint4*)&vt[ca>>3][(ca&7)*8] = u0;
        *(uint4*)&vt[cb>>3][(cb&7)*8] = u1;
      }
      __syncthreads();
      // S = Q K^T (16x64 per wave)
      f32x4 sacc[4];
      for (int c=0;c<4;++c) sacc[c] = (f32x4){0.f,0.f,0.f,0.f};
      for (int c=0;c<4;++c) {
        int mg = t*64 + c*16 + lr;
        const u16* kp = kh + base + (size_t)mg*64 + lkg*8;
        sacc[c] = __builtin_amdgcn_mfma_f32_16x16x32_bf16(qa[0], ld8(kp),    sacc[c], 0,0,0);
        sacc[c] = __builtin_amdgcn_mfma_f32_16x16x32_bf16(qa[1], ld8(kp+32), sacc[c], 0,0,0);
      }
      // P = S * fac * tf (mask on diagonal tile)
      if (t == qt) {
        #pragma unroll
        for (int c=0;c<4;++c)
          #pragma unroll
          for (int r=0;r<4;++r) {
            int d = (nl_base + r) - (c*16 + lr);
            float p = (d >= 0) ? sacc[c][r]*fac[c][r] : 0.0f;
            pl[w][lkg*4+r][c*16+lr] = f2bf(p);
          }
      } else {
        #pragma unroll
        for (int c=0;c<4;++c)
          #pragma unroll
          for (int r=0;r<4;++r)
            pl[w][lkg*4+r][c*16+lr] = f2bf(sacc[c][r]*fac[c][r]*tf);
      }
      tf *= g64inv;
      // PV
      for (int kk=0;kk<2;++kk) {
        bf16x8 pa = *(bf16x8*)&pl[w][lr][kk*32 + lkg*8];
        #pragma unroll
        for (int eb=0;eb<4;++eb) {
          bf16x8 vb = *(bf16x8*)&vt[eb*16+lr][kk*32 + lkg*8];
          yacc[eb] = __builtin_amdgcn_mfma_f32_16x16x32_bf16(pa, vb, yacc[eb], 0,0,0);
        }
      }
    }
    for (int eb=0;eb<4;++eb) {
      #pragma unroll
      for (int r=0;r<4;++r) {
        int n = nrow + r;
        int col = h*64 + eb*16 + lr;
        y[((size_t)(b*N_+n))*D_ + col] = yacc[eb][r];
      }
    }
  }
}

// ---------- row LayerNorm(y)*g -> z, plus per-row z sums ----------
__global__ void k_ln_mul(const float* __restrict__ y, const float* __restrict__ g,
                         const float* __restrict__ lnw, const float* __restrict__ lnb,
                         float* __restrict__ z, double* __restrict__ zrow) {
  int m = blockIdx.x, t = threadIdx.x;
  float4 v = *(const float4*)(y + (size_t)m*D_ + t*4);
  double s  = (double)v.x + (double)v.y + (double)v.z + (double)v.w;
  double s2 = (double)v.x*v.x + (double)v.y*v.y + (double)v.z*v.z + (double)v.w*v.w;
  __shared__ double lds[8];
  int w = t>>6, l = t&63;
  for (int o = 32; o > 0; o >>= 1) { s += __shfl_down(s,o); s2 += __shfl_down(s2,o); }
  if (l==0) { lds[w*2]=s; lds[w*2+1]=s2; }
  __syncthreads();
  double ts = lds[0]+lds[2]+lds[4]+lds[6], ts2 = lds[1]+lds[3]+lds[5]+lds[7];
  float mu = (float)(ts/(double)D_);
  float var = (float)(ts2/(double)D_) - mu*mu;
  float rstd = rsqrtf(var + 1e-5f);
  float4 gv = *(const float4*)(g + (size_t)m*D_ + t*4);
  float4 lw = *(const float4*)(lnw + t*4);
  float4 lb = *(const float4*)(lnb + t*4);
  float z0 = ((v.x-mu)*rstd*lw.x + lb.x)*gv.x;
  float z1 = ((v.y-mu)*rstd*lw.y + lb.y)*gv.y;
  float z2 = ((v.z-mu)*rstd*lw.z + lb.z)*gv.z;
  float z3 = ((v.w-mu)*rstd*lw.w + lb.w)*gv.w;
  float4 zo; zo.x=z0; zo.y=z1; zo.z=z2; zo.w=z3;
  *(float4*)(z + (size_t)m*D_ + t*4) = zo;
  double zs  = (double)z0 + (double)z1 + (double)z2 + (double)z3;
  double zs2 = (double)z0*z0 + (double)z1*z1 + (double)z2*z2 + (double)z3*z3;
  for (int o = 32; o > 0; o >>= 1) { zs += __shfl_down(zs,o); zs2 += __shfl_down(zs2,o); }
  __syncthreads();
  if (l==0) { lds[w*2]=zs; lds[w*2+1]=zs2; }
  __syncthreads();
  if (t==0) {
    zrow[m*2]   = lds[0]+lds[2]+lds[4]+lds[6];
    zrow[m*2+1] = lds[1]+lds[3]+lds[5]+lds[7];
  }
}

__global__ void k_zstats_final(const double* __restrict__ zrow, float* __restrict__ stats) {
  int b = blockIdx.x, t = threadIdx.x; // 256
  double s=0.0, s2=0.0;
  for (int k=0;k<8;++k) {
    int m = b*2048 + k*256 + t;
    s += zrow[m*2]; s2 += zrow[m*2+1];
  }
  for (int o = 32; o > 0; o >>= 1) { s += __shfl_down(s,o); s2 += __shfl_down(s2,o); }
  __shared__ double lds[8];
  int w = t>>6, l = t&63;
  if (l==0) { lds[w*2]=s; lds[w*2+1]=s2; }
  __syncthreads();
  if (t==0) {
    double ts = lds[0]+lds[2]+lds[4]+lds[6], ts2 = lds[1]+lds[3]+lds[5]+lds[7];
    double inv = 1.0/(double)(N_*D_);
    double mu = ts*inv, var = ts2*inv - mu*mu;
    stats[b*2]   = (float)mu;
    stats[b*2+1] = rsqrtf((float)var + 1e-5f);
  }
}

extern "C" void kernel_launch(void* const* d_in, const int* in_sizes, int n_in,
                              void* d_out, int out_size, void* d_ws, size_t ws_size,
                              hipStream_t stream) {
  const float* x = (const float*)d_in[0];
  Ptr5 W;
  for (int i = 0; i < 5; ++i) W.p[i] = (const float*)d_in[1+i];
  const float* lnw = (const float*)d_in[6];
  const float* lnb = (const float*)d_in[7];

  char* ws = (char*)d_ws;
  float*  xstats = (float*)(ws + 0);
  float*  zstats = (float*)(ws + 64);
  float*  mw     = (float*)(ws + 128);
  float*  invmw  = (float*)(ws + 192);
  double* part1  = (double*)(ws + 256);      // 128*2 doubles
  double* wpart  = (double*)(ws + 2304);     // 80 doubles
  float*  inv1   = (float*)(ws + 3072);      // 4096
  float*  inv2   = (float*)(ws + 19456);     // 4096
  double* zrow   = (double*)(ws + 35840);    // 4096*2
  u16*    wt     = (u16*)(ws + 101376);      // 5*1M bf16
  u16*    qx     = (u16*)(ws + 10587136);    // 4096x1024 bf16
  u16*    qh     = (u16*)(ws + 18975744);
  u16*    kh     = (u16*)(ws + 27364352);
  u16*    vhT    = (u16*)(ws + 35752960);    // [B,H,64,N]
  float*  gbuf   = (float*)(ws + 44141568);
  float*  ybuf   = (float*)(ws + 60918784);
  float*  zbuf   = (float*)(ws + 77696000);
  u16*    qz     = qx; // reuse

  GammaArg G;
  {
    double l0 = log(1.0/32.0), l1 = log(1.0/512.0);
    for (int h = 0; h < 16; ++h) {
      float t = (float)(l0 + (l1-l0)*((double)h/15.0));
      float gm = 1.0f - expf(t);
      G.lg2[h] = (float)log2((double)gm);
    }
  }

  dim3 b256(256);
  hipLaunchKernelGGL(k_batch_stats_partial, dim3(64, B_), b256, 0, stream, x, part1);
  hipLaunchKernelGGL(k_batch_stats_final, dim3(B_), dim3(64), 0, stream, part1, xstats);
  hipLaunchKernelGGL(k_wmean_partial, dim3(16, 5), b256, 0, stream, W, wpart);
  hipLaunchKernelGGL(k_wmean_final, dim3(5), dim3(64), 0, stream, wpart, mw, invmw);
  hipLaunchKernelGGL(k_ternarize, dim3(1024, 5), b256, 0, stream, W, invmw, wt);
  hipLaunchKernelGGL(k_quant_rows, dim3(M_), b256, 0, stream, x, xstats, qx, inv1);

  hipLaunchKernelGGL(k_gemm, dim3(32,16), b256, 0, stream, qx, wt + (size_t)0*1048576, inv1, mw, 0, (float*)nullptr, qh, 2);
  hipLaunchKernelGGL(k_gemm, dim3(32,16), b256, 0, stream, qx, wt + (size_t)1*1048576, inv1, mw, 1, (float*)nullptr, kh, 2);
  hipLaunchKernelGGL(k_gemm, dim3(32,16), b256, 0, stream, qx, wt + (size_t)2*1048576, inv1, mw, 2, (float*)nullptr, vhT, 3);
  hipLaunchKernelGGL(k_gemm, dim3(32,16), b256, 0, stream, qx, wt + (size_t)3*1048576, inv1, mw, 3, gbuf, (u16*)nullptr, 1);

  hipLaunchKernelGGL(k_attn, dim3(16, 32), b256, 0, stream, qh, kh, vhT, ybuf, G);

  hipLaunchKernelGGL(k_ln_mul, dim3(M_), b256, 0, stream, ybuf, gbuf, lnw, lnb, zbuf, zrow);
  hipLaunchKernelGGL(k_zstats_final, dim3(B_), b256, 0, stream, zrow, zstats);
  hipLaunchKernelGGL(k_quant_rows, dim3(M_), b256, 0, stream, zbuf, zstats, qz, inv2);
  hipLaunchKernelGGL(k_gemm, dim3(32,16), b256, 0, stream, qz, wt + (size_t)4*1048576, inv2, mw, 4, (float*)d_out, (u16*)nullptr, 0);
}